// Round 1
// baseline (4089.733 us; speedup 1.0000x reference)
//
#include <hip/hip_runtime.h>
#include <hip/hip_bf16.h>

#define TT 128
#define BB 128
#define HH 1024
#define PP 32
#define G7 7168

typedef __attribute__((ext_vector_type(8))) short short8;
typedef __attribute__((ext_vector_type(4))) float f32x4;

__device__ __forceinline__ ushort f2bf(float f) {
    union { float f; unsigned int u; } v; v.f = f;
    unsigned int u = v.u;
    unsigned int r = (u + 0x7FFFu + ((u >> 16) & 1u)) >> 16;
    return (ushort)r;
}

// ---- prep: transpose W rows 32..1055 -> Wt[7168][1024] bf16 ----
__global__ void prep_transpose(const float* __restrict__ W, ushort* __restrict__ Wt) {
    __shared__ float tile[32][33];
    int k0 = blockIdx.x * 32;   // k in [0,1024)
    int n0 = blockIdx.y * 32;   // n in [0,7168)
    int tx = threadIdx.x, ty = threadIdx.y;
    for (int r = ty; r < 32; r += 8)
        tile[r][tx] = W[(size_t)(32 + k0 + r) * G7 + n0 + tx];
    __syncthreads();
    for (int r = ty; r < 32; r += 8)
        Wt[(size_t)(n0 + r) * HH + k0 + tx] = f2bf(tile[tx][r]);
}

// ---- prep: G0[type][n] = b[n] + embed[type] @ W[0:32] ----
__global__ void prep_g0(const float* __restrict__ W, const float* __restrict__ embed,
                        const float* __restrict__ bias, float* __restrict__ G0) {
    int n = blockIdx.x * 256 + threadIdx.x;
    int ty = blockIdx.y;
    float acc = bias[n];
    for (int p = 0; p < PP; ++p)
        acc += embed[ty * PP + p] * W[(size_t)p * G7 + n];
    G0[(size_t)ty * G7 + n] = acc;
}

// ---- prep: init states ----
__global__ void prep_init(const float* __restrict__ h0, const float* __restrict__ c0,
                          ushort* __restrict__ h_state, float* __restrict__ c_state,
                          float* __restrict__ ctgt_state) {
    int i = blockIdx.x * 256 + threadIdx.x;
    h_state[i] = f2bf(h0[i]);
    c_state[i] = c0[i];
    ctgt_state[i] = c0[i];
}

// ---- per-step fused kernel: 7 waves (one gate each), 32b x 32h tile ----
__global__ __launch_bounds__(448) void step_kernel(
    const ushort* __restrict__ Wt, const float* __restrict__ G0,
    const float* __restrict__ dts, const int* __restrict__ types,
    const ushort* __restrict__ h_read, ushort* __restrict__ h_write,
    float* __restrict__ c_state, float* __restrict__ ctgt_state,
    float* __restrict__ out, int t)
{
    __shared__ float gbuf[7][32][32];
    const int tid = threadIdx.x;
    const int g = tid >> 6;           // gate = wave index 0..6
    const int lane = tid & 63;
    const int b0 = blockIdx.y * 32;
    const int h0i = blockIdx.x * 32;
    const int lr = lane & 15;         // row/col within 16x16 frag
    const int lk = (lane >> 4) * 8;   // k sub-offset

    f32x4 acc00 = {}, acc01 = {}, acc10 = {}, acc11 = {};

    const short8* pa0 = reinterpret_cast<const short8*>(h_read + (size_t)(b0 + lr) * HH + lk);
    const short8* pa1 = reinterpret_cast<const short8*>(h_read + (size_t)(b0 + 16 + lr) * HH + lk);
    const short8* pb0 = reinterpret_cast<const short8*>(Wt + (size_t)(g * HH + h0i + lr) * HH + lk);
    const short8* pb1 = reinterpret_cast<const short8*>(Wt + (size_t)(g * HH + h0i + 16 + lr) * HH + lk);

    #pragma unroll 4
    for (int kk = 0; kk < HH; kk += 32) {
        int idx = kk >> 3;      // in units of short8 (8 bf16)
        short8 a0 = pa0[idx];
        short8 a1 = pa1[idx];
        short8 bf0 = pb0[idx];
        short8 bf1 = pb1[idx];
        acc00 = __builtin_amdgcn_mfma_f32_16x16x32_bf16(a0, bf0, acc00, 0, 0, 0);
        acc01 = __builtin_amdgcn_mfma_f32_16x16x32_bf16(a0, bf1, acc01, 0, 0, 0);
        acc10 = __builtin_amdgcn_mfma_f32_16x16x32_bf16(a1, bf0, acc10, 0, 0, 0);
        acc11 = __builtin_amdgcn_mfma_f32_16x16x32_bf16(a1, bf1, acc11, 0, 0, 0);
    }

    // C/D layout (m89-verified): col = lane&15, row = (lane>>4)*4 + r
    const int rb = (lane >> 4) * 4;
    #pragma unroll
    for (int r = 0; r < 4; ++r) {
        gbuf[g][rb + r][lr]           = acc00[r];
        gbuf[g][rb + r][16 + lr]      = acc01[r];
        gbuf[g][16 + rb + r][lr]      = acc10[r];
        gbuf[g][16 + rb + r][16 + lr] = acc11[r];
    }
    __syncthreads();

    const size_t OS = (size_t)TT * BB * HH;
    for (int e = tid; e < 1024; e += 448) {
        int br = e >> 5, hc = e & 31;
        int b = b0 + br, h = h0i + hc;
        int ty = types[t * BB + b];
        float dt = dts[t * BB + b];
        const float* g0p = G0 + (size_t)ty * G7 + h;
        float pre[7];
        #pragma unroll
        for (int gg = 0; gg < 7; ++gg)
            pre[gg] = gbuf[gg][br][hc] + g0p[gg * HH];

        float inpt   = 1.f / (1.f + __expf(-pre[0]));
        float forget = 1.f / (1.f + __expf(-pre[1]));
        float output = 1.f / (1.f + __expf(-pre[2]));
        float itg    = 1.f / (1.f + __expf(-pre[3]));
        float ftg    = 1.f / (1.f + __expf(-pre[4]));
        float z      = tanhf(pre[5]);
        float x8     = 8.f * pre[6];
        float sp     = fmaxf(x8, 0.f) + log1pf(__expf(-fabsf(x8)));
        float decay  = sp * 0.125f;

        size_t si = (size_t)b * HH + h;
        float c    = c_state[si];
        float ctgt = ctgt_state[si];
        float c_i      = forget * c + inpt * z;
        float h_i      = output * tanhf(c_i);
        float ctgt_new = ftg * ctgt + itg * z;
        float edt      = __expf(-decay * dt);
        float c_new    = ctgt_new + (c_i - ctgt_new) * edt;
        float h_new    = output * tanhf(c_new);

        size_t ob = (size_t)t * BB * HH + si;
        out[ob]          = h_i;
        out[OS + ob]     = h_new;
        out[2 * OS + ob] = output;
        out[3 * OS + ob] = c_i;
        out[4 * OS + ob] = ctgt_new;
        out[5 * OS + ob] = decay;
        c_state[si]    = c_new;
        ctgt_state[si] = ctgt_new;
        h_write[si]    = f2bf(h_new);
    }
}

extern "C" void kernel_launch(void* const* d_in, const int* in_sizes, int n_in,
                              void* d_out, int out_size, void* d_ws, size_t ws_size,
                              hipStream_t stream) {
    const float* seq_dt    = (const float*)d_in[0];
    const int*   seq_types = (const int*)d_in[1];
    const float* h0        = (const float*)d_in[2];
    const float* c0        = (const float*)d_in[3];
    const float* embed     = (const float*)d_in[4];
    const float* W         = (const float*)d_in[5];
    const float* bias      = (const float*)d_in[6];
    float* out = (float*)d_out;

    char* ws = (char*)d_ws;
    ushort* Wt        = (ushort*)ws;                 // 7168*1024*2 = 14,680,064
    float*  G0        = (float*)(ws + 14680064);     // 33*7168*4  =    946,176
    ushort* hs0       = (ushort*)(ws + 15626240);    // 128*1024*2 =    262,144
    ushort* hs1       = (ushort*)(ws + 15888384);    //                 262,144
    float*  c_state   = (float*)(ws + 16150528);     // 128*1024*4 =    524,288
    float*  ctgt_state= (float*)(ws + 16674816);     //                 524,288

    hipLaunchKernelGGL(prep_transpose, dim3(32, 224), dim3(32, 8), 0, stream, W, Wt);
    hipLaunchKernelGGL(prep_g0, dim3(28, 33), dim3(256), 0, stream, W, embed, bias, G0);
    hipLaunchKernelGGL(prep_init, dim3(512), dim3(256), 0, stream, h0, c0, hs0, c_state, ctgt_state);

    for (int t = 0; t < TT; ++t) {
        const ushort* hr = (t & 1) ? hs1 : hs0;
        ushort*       hw = (t & 1) ? hs0 : hs1;
        hipLaunchKernelGGL(step_kernel, dim3(32, 4), dim3(448), 0, stream,
                           Wt, G0, seq_dt, seq_types, hr, hw, c_state, ctgt_state, out, t);
    }
}

// Round 2
// 1745.744 us; speedup vs baseline: 2.3427x; 2.3427x over previous
//
#include <hip/hip_runtime.h>
#include <hip/hip_bf16.h>

#define TT 128
#define BB 128
#define HH 1024
#define PP 32
#define G7 7168

typedef __attribute__((ext_vector_type(8))) short short8;
typedef __attribute__((ext_vector_type(4))) float f32x4;

__device__ __forceinline__ ushort f2bf(float f) {
    union { float f; unsigned int u; } v; v.f = f;
    unsigned int u = v.u;
    return (ushort)((u + 0x7FFFu + ((u >> 16) & 1u)) >> 16);
}
__device__ __forceinline__ float sigm(float x) { return 1.f / (1.f + __expf(-x)); }
__device__ __forceinline__ float ftanh(float x) {
    float e = __expf(2.f * x);
    return 1.f - 2.f / (e + 1.f);
}

// ---- prep: repack W rows 32..1055 into MFMA-fragment-major bf16 layout ----
// W2[(nt*32 + ki)*64 + lane][e] = W[32 + ki*32 + (lane>>4)*8 + e][nt*16 + (lane&15)]
__global__ void prep_w2(const float* __restrict__ W, ushort* __restrict__ W2) {
    int nt = blockIdx.x;          // 0..447 (n-tile of 16 cols)
    int ki = blockIdx.y;          // 0..31  (k-chunk of 32)
    int lane = threadIdx.x;       // 0..63
    int n = nt * 16 + (lane & 15);
    int k = ki * 32 + (lane >> 4) * 8;
    size_t off = ((size_t)(nt * 32 + ki) * 64 + lane) * 8;
    #pragma unroll
    for (int e = 0; e < 8; ++e)
        W2[off + e] = f2bf(W[(size_t)(32 + k + e) * G7 + n]);
}

// ---- prep: G0[type][n] = b[n] + embed[type] @ W[0:32] ----
__global__ void prep_g0(const float* __restrict__ W, const float* __restrict__ embed,
                        const float* __restrict__ bias, float* __restrict__ G0) {
    int n = blockIdx.x * 256 + threadIdx.x;
    int ty = blockIdx.y;
    float acc = bias[n];
    for (int p = 0; p < PP; ++p)
        acc += embed[ty * PP + p] * W[(size_t)p * G7 + n];
    G0[(size_t)ty * G7 + n] = acc;
}

// ---- prep: init states; h0 into fragment-major A layout ----
__global__ void prep_init(const float* __restrict__ h0, const float* __restrict__ c0,
                          ushort* __restrict__ A2, float* __restrict__ c_state,
                          float* __restrict__ ctgt_state) {
    int i = blockIdx.x * 256 + threadIdx.x;  // over 128*1024
    int b = i >> 10, h = i & 1023;
    int lane = (b & 15) | (((h >> 3) & 3) << 4);
    size_t off = ((size_t)((b >> 4) * 32 + (h >> 5)) * 64 + lane) * 8 + (h & 7);
    A2[off] = f2bf(h0[i]);
    c_state[i] = c0[i];
    ctgt_state[i] = c0[i];
}

// ---- per-step fused kernel: 256 blocks, 7 waves (one gate each), 32b x 16h ----
__global__ __launch_bounds__(448) void step_kernel(
    const ushort* __restrict__ W2, const float* __restrict__ G0,
    const float* __restrict__ dts, const int* __restrict__ types,
    const ushort* __restrict__ a_read, ushort* __restrict__ a_write,
    float* __restrict__ c_state, float* __restrict__ ctgt_state,
    float* __restrict__ out, int t)
{
    __shared__ float gbuf[7][32][16];
    const int tid = threadIdx.x;
    const int g = tid >> 6;            // gate = wave 0..6
    const int lane = tid & 63;
    // XCD-pinned decode: blocks with bid%8==x land on XCD x (round-robin dispatch);
    // give XCD x the h-cols [x*128, x*128+127] so its W2 slice (1.79 MB) stays L2-resident.
    const int bid = blockIdx.x;
    const int xcd = bid & 7;
    const int loc = bid >> 3;          // 0..31
    const int ht  = xcd * 8 + (loc & 7);   // h-tile 0..63 (16 cols each)
    const int btile = loc >> 3;        // 0..3 (32 rows each)
    const int h0i = ht * 16;
    const int b0 = btile * 32;

    f32x4 acc0 = {}, acc1 = {};
    const int nt = g * 64 + ht;        // n-tile of this gate's 16 cols
    const short8* A2v = reinterpret_cast<const short8*>(a_read);
    const short8* W2v = reinterpret_cast<const short8*>(W2);
    const int baseA0 = (btile * 2) * 32 * 64 + lane;
    const int baseA1 = (btile * 2 + 1) * 32 * 64 + lane;
    const int baseB  = nt * 32 * 64 + lane;

    #pragma unroll 8
    for (int ki = 0; ki < 32; ++ki) {
        short8 a0 = A2v[baseA0 + ki * 64];
        short8 a1 = A2v[baseA1 + ki * 64];
        short8 bf = W2v[baseB + ki * 64];
        acc0 = __builtin_amdgcn_mfma_f32_16x16x32_bf16(a0, bf, acc0, 0, 0, 0);
        acc1 = __builtin_amdgcn_mfma_f32_16x16x32_bf16(a1, bf, acc1, 0, 0, 0);
    }

    // C/D layout: col = lane&15, row = (lane>>4)*4 + r (m89-verified, same as R1)
    const int rb = (lane >> 4) * 4;
    const int lr = lane & 15;
    #pragma unroll
    for (int r = 0; r < 4; ++r) {
        gbuf[g][rb + r][lr]      = acc0[r];
        gbuf[g][16 + rb + r][lr] = acc1[r];
    }
    __syncthreads();

    const size_t OS = (size_t)TT * BB * HH;
    for (int e = tid; e < 512; e += 448) {
        int br = e >> 4, hc = e & 15;
        int b = b0 + br, h = h0i + hc;
        int ty = types[t * BB + b];
        float dt = dts[t * BB + b];
        const float* g0p = G0 + (size_t)ty * G7 + h;
        float pre[7];
        #pragma unroll
        for (int gg = 0; gg < 7; ++gg)
            pre[gg] = gbuf[gg][br][hc] + g0p[gg * HH];

        float inpt   = sigm(pre[0]);
        float forget = sigm(pre[1]);
        float output = sigm(pre[2]);
        float itg    = sigm(pre[3]);
        float ftg    = sigm(pre[4]);
        float z      = ftanh(pre[5]);
        float x8     = 8.f * pre[6];
        float sp     = fmaxf(x8, 0.f) + __logf(1.f + __expf(-fabsf(x8)));
        float decay  = sp * 0.125f;

        size_t si = (size_t)b * HH + h;
        float c    = c_state[si];
        float ctgt = ctgt_state[si];
        float c_i      = forget * c + inpt * z;
        float h_i      = output * ftanh(c_i);
        float ctgt_new = ftg * ctgt + itg * z;
        float edt      = __expf(-decay * dt);
        float c_new    = ctgt_new + (c_i - ctgt_new) * edt;
        float h_new    = output * ftanh(c_new);

        size_t ob = (size_t)t * BB * HH + si;
        out[ob]          = h_i;
        out[OS + ob]     = h_new;
        out[2 * OS + ob] = output;
        out[3 * OS + ob] = c_i;
        out[4 * OS + ob] = ctgt_new;
        out[5 * OS + ob] = decay;
        c_state[si]    = c_new;
        ctgt_state[si] = ctgt_new;
        // h_new into fragment-major A layout for next step's coalesced loads
        int lane_w = (b & 15) | (((h >> 3) & 3) << 4);
        size_t aoff = ((size_t)((b >> 4) * 32 + (h >> 5)) * 64 + lane_w) * 8 + (h & 7);
        a_write[aoff] = f2bf(h_new);
    }
}

extern "C" void kernel_launch(void* const* d_in, const int* in_sizes, int n_in,
                              void* d_out, int out_size, void* d_ws, size_t ws_size,
                              hipStream_t stream) {
    const float* seq_dt    = (const float*)d_in[0];
    const int*   seq_types = (const int*)d_in[1];
    const float* h0        = (const float*)d_in[2];
    const float* c0        = (const float*)d_in[3];
    const float* embed     = (const float*)d_in[4];
    const float* W         = (const float*)d_in[5];
    const float* bias      = (const float*)d_in[6];
    float* out = (float*)d_out;

    char* ws = (char*)d_ws;
    ushort* W2        = (ushort*)ws;                 // 7168*1024*2 = 14,680,064
    float*  G0        = (float*)(ws + 14680064);     // 33*7168*4  =    946,176
    ushort* hs0       = (ushort*)(ws + 15626240);    // 128*1024*2 =    262,144
    ushort* hs1       = (ushort*)(ws + 15888384);    //                 262,144
    float*  c_state   = (float*)(ws + 16150528);     // 128*1024*4 =    524,288
    float*  ctgt_state= (float*)(ws + 16674816);     //                 524,288

    hipLaunchKernelGGL(prep_w2, dim3(448, 32), dim3(64), 0, stream, W, W2);
    hipLaunchKernelGGL(prep_g0, dim3(28, 33), dim3(256), 0, stream, W, embed, bias, G0);
    hipLaunchKernelGGL(prep_init, dim3(512), dim3(256), 0, stream, h0, c0, hs0, c_state, ctgt_state);

    for (int t = 0; t < TT; ++t) {
        const ushort* hr = (t & 1) ? hs1 : hs0;
        ushort*       hw = (t & 1) ? hs0 : hs1;
        hipLaunchKernelGGL(step_kernel, dim3(256), dim3(448), 0, stream,
                           W2, G0, seq_dt, seq_types, hr, hw, c_state, ctgt_state, out, t);
    }
}